// Round 5
// baseline (224.842 us; speedup 1.0000x reference)
//
#include <hip/hip_runtime.h>
#include <stdint.h>

// Problem constants: B=32, T=512, F=513, S=3
#define BB 32
#define NN (512 * 513)                     // 262656 elements per (b, source)
#define FLOATS_PER_B (NN * 3)              // 787968 floats per batch slice
#define CHUNKS_PER_B (FLOATS_PER_B / 12)   // 65664 = 128 * 513 chunks of 12 floats
#define THREADS 128                        // 2 waves
#define TILE_CHUNKS 128                    // chunks per tile (1 per thread)
#define TILE_FLOATS (TILE_CHUNKS * 12)     // 1536 floats = 6144 B per array
#define TILES_PER_B 513
#define TILES_PER_BLOCK 9
#define BLOCKS_PER_B 57                    // 57 * 9 = 513, exact

typedef unsigned int u32;
typedef const __attribute__((address_space(1))) u32* gptr_t;
typedef __attribute__((address_space(3))) u32* lptr_t;

// One wave-level DMA: each lane contributes 16 B; lands at lds + lane*16.
__device__ __forceinline__ void dma16(const float* g, float* lds_uniform) {
    __builtin_amdgcn_global_load_lds((gptr_t)(const void*)g,
                                     (lptr_t)(void*)lds_uniform, 16, 0, 0);
}

// Stage one tile (est + tgt, 6 KB each) into LDS via 12 x 1KB DMA calls.
__device__ __forceinline__ void prefetch_tile(
        const float* __restrict__ eb, const float* __restrict__ tb,
        int tile, float* se, float* st, int wave, int lane) {
    const float* ge = eb + (size_t)tile * TILE_FLOATS;
    const float* gt = tb + (size_t)tile * TILE_FLOATS;
#pragma unroll
    for (int q = 0; q < 3; ++q) {
        const int off = wave * (TILE_FLOATS / 2) + q * 256;  // floats
        dma16(ge + off + lane * 4, se + off);
        dma16(gt + off + lane * 4, st + off);
    }
}

// --- Kernel 1: per-block partial sums via async global->LDS DMA staging ---
__global__ __launch_bounds__(THREADS) void pil_partial(
        const float* __restrict__ est,
        const float* __restrict__ tgt,
        float* __restrict__ ws) {
    const int b    = blockIdx.x / BLOCKS_PER_B;
    const int blk  = blockIdx.x % BLOCKS_PER_B;
    const int tid  = threadIdx.x;
    const int wave = tid >> 6;
    const int lane = tid & 63;

    const float* eb = est + (size_t)b * FLOATS_PER_B;
    const float* tb = tgt + (size_t)b * FLOATS_PER_B;
    const int tile0 = blk * TILES_PER_BLOCK;

    __shared__ float se[2][TILE_FLOATS];
    __shared__ float st[2][TILE_FLOATS];

    float acc[9];
#pragma unroll
    for (int k = 0; k < 9; ++k) acc[k] = 0.0f;

    prefetch_tile(eb, tb, tile0, se[0], st[0], wave, lane);

    for (int k = 0; k < TILES_PER_BLOCK; ++k) {
        __syncthreads();  // drains DMA queue: tile k's data is in LDS; buffer
                          // (k+1)&1's readers from iter k-1 are also done.
        if (k + 1 < TILES_PER_BLOCK)
            prefetch_tile(eb, tb, tile0 + k + 1, se[(k + 1) & 1],
                          st[(k + 1) & 1], wave, lane);

        // Compute chunk `tid` of tile k: 12 contiguous floats per array.
        const float* ep = se[k & 1] + tid * 12;
        const float* tp = st[k & 1] + tid * 12;
        const float4 a0 = *(const float4*)(ep);
        const float4 a1 = *(const float4*)(ep + 4);
        const float4 a2 = *(const float4*)(ep + 8);
        const float4 b0 = *(const float4*)(tp);
        const float4 b1 = *(const float4*)(tp + 4);
        const float4 b2 = *(const float4*)(tp + 8);
        const float e[12] = {a0.x, a0.y, a0.z, a0.w, a1.x, a1.y,
                             a1.z, a1.w, a2.x, a2.y, a2.z, a2.w};
        const float t[12] = {b0.x, b0.y, b0.z, b0.w, b1.x, b1.y,
                             b1.z, b1.w, b2.x, b2.y, b2.z, b2.w};
#pragma unroll
        for (int g = 0; g < 4; ++g) {
#pragma unroll
            for (int i = 0; i < 3; ++i) {
#pragma unroll
                for (int j = 0; j < 3; ++j) {
                    acc[i * 3 + j] += fabsf(e[3 * g + i] - t[3 * g + j]);
                }
            }
        }
    }

    // Wave-level reduction (64 lanes) of each of the 9 accumulators.
#pragma unroll
    for (int k = 0; k < 9; ++k) {
        float v = acc[k];
#pragma unroll
        for (int off = 32; off > 0; off >>= 1) v += __shfl_down(v, off);
        acc[k] = v;
    }

    __shared__ float sred[2][9];
    if (lane == 0) {
#pragma unroll
        for (int k = 0; k < 9; ++k) sred[wave][k] = acc[k];
    }
    __syncthreads();
    if (tid < 9)
        ws[(size_t)(b * BLOCKS_PER_B + blk) * 9 + tid] =
            sred[0][tid] + sred[1][tid];
}

// --- Kernel 2: sum block partials, per-b perm losses, min, mean over b ---
__global__ void pil_finalize(const float* __restrict__ ws, float* __restrict__ out) {
    __shared__ float sC[BB][9];
    const int p = threadIdx.x;  // 320 threads; first 288 sum partials
    if (p < BB * 9) {
        const int b = p / 9, k = p % 9;
        float s = 0.0f;
        for (int blk = 0; blk < BLOCKS_PER_B; ++blk)
            s += ws[(size_t)(b * BLOCKS_PER_B + blk) * 9 + k];
        sC[b][k] = s;
    }
    __syncthreads();

    if (p < 64) {  // wave 0 only
        float loss = 0.0f;
        if (p < BB) {
            float C[3][3];
#pragma unroll
            for (int i = 0; i < 3; ++i)
#pragma unroll
                for (int j = 0; j < 3; ++j)
                    C[i][j] = sC[p][i * 3 + j] * (1.0f / (float)NN);

            const int P[6][3] = {{0, 1, 2}, {0, 2, 1}, {1, 0, 2},
                                 {1, 2, 0}, {2, 0, 1}, {2, 1, 0}};
            float best = 3.4e38f;
#pragma unroll
            for (int q = 0; q < 6; ++q) {
                float l = (C[P[q][0]][0] + C[P[q][1]][1] + C[P[q][2]][2]) *
                          (1.0f / 3.0f);
                best = fminf(best, l);
            }
            loss = best;
        }
#pragma unroll
        for (int off = 32; off > 0; off >>= 1) loss += __shfl_down(loss, off);
        if (p == 0) out[0] = loss * (1.0f / (float)BB);
    }
}

extern "C" void kernel_launch(void* const* d_in, const int* in_sizes, int n_in,
                              void* d_out, int out_size, void* d_ws, size_t ws_size,
                              hipStream_t stream) {
    const float* est = (const float*)d_in[0];
    const float* tgt = (const float*)d_in[1];
    float* ws  = (float*)d_ws;   // 32*57*9 floats = 65664 B of scratch
    float* out = (float*)d_out;

    pil_partial<<<BB * BLOCKS_PER_B, THREADS, 0, stream>>>(est, tgt, ws);
    pil_finalize<<<1, 320, 0, stream>>>(ws, out);
}